// Round 1
// baseline (3034.649 us; speedup 1.0000x reference)
//
#include <hip/hip_runtime.h>

#define N_PTS 1048576
#define NC 50000

// ---------------- point MLP: fc1 (4->64), fc2 (64->128), segment-max ----------------
__global__ __launch_bounds__(256) void k_points(
    const float* __restrict__ inv_feats, const int* __restrict__ cluster,
    const float* __restrict__ W1, const float* __restrict__ b1,
    const float* __restrict__ W2, const float* __restrict__ b2,
    float* __restrict__ mx)
{
    int i = blockIdx.x * 256 + threadIdx.x;
    if (i >= N_PTS) return;
    const float4 xf = *(const float4*)(inv_feats + (size_t)i * 4);
    const int c = cluster[i];

    float fc1[64];
#pragma unroll
    for (int k = 0; k < 64; ++k) {
        float acc = b1[k];
        acc = fmaf(W1[k * 4 + 0], xf.x, acc);
        acc = fmaf(W1[k * 4 + 1], xf.y, acc);
        acc = fmaf(W1[k * 4 + 2], xf.z, acc);
        acc = fmaf(W1[k * 4 + 3], xf.w, acc);
        fc1[k] = fmaxf(acc, 0.f);
    }

    int* mrow = (int*)(mx + (size_t)c * 128);
    for (int k = 0; k < 128; ++k) {
        float acc = b2[k];
#pragma unroll
        for (int j = 0; j < 64; ++j)
            acc = fmaf(W2[k * 64 + j], fc1[j], acc);
        // relu'd value; mx initialized to 0, so only positive values need atomics.
        // values >= 0 -> int bit pattern ordering == float ordering.
        if (acc > 0.f)
            atomicMax(mrow + k, __float_as_int(acc));
    }
}

// ---------------- cluster MLP: fc3 (128->64), fc4 (64->64) ----------------
__global__ __launch_bounds__(256) void k_cluster(
    const float* __restrict__ mx,
    const float* __restrict__ W3, const float* __restrict__ b3,
    const float* __restrict__ W4, const float* __restrict__ b4,
    float* __restrict__ fc4out)
{
    __shared__ float sW3T[128 * 64];  // W3T[j][k] = W3[k][j], 32 KB
    __shared__ float sW4T[64 * 64];   // W4T[j][k] = W4[k][j], 16 KB
    __shared__ float sF3[4][64];

    for (int t = threadIdx.x; t < 128 * 64; t += 256) {
        int r = t >> 7, cc = t & 127;        // W3 row r (out ch), col cc (in ch)
        sW3T[cc * 64 + r] = W3[t];
    }
    for (int t = threadIdx.x; t < 64 * 64; t += 256) {
        int r = t >> 6, cc = t & 63;
        sW4T[cc * 64 + r] = W4[t];
    }
    __syncthreads();

    const int wave = threadIdx.x >> 6;
    const int lane = threadIdx.x & 63;

    for (int base = blockIdx.x * 4; base < NC; base += gridDim.x * 4) {
        int c = base + wave;
        bool act = c < NC;
        int cs = __builtin_amdgcn_readfirstlane(act ? c : 0);
        const float* mrow = mx + (size_t)cs * 128;   // wave-uniform -> scalar loads

        float acc = b3[lane];
#pragma unroll 8
        for (int j = 0; j < 128; ++j)
            acc = fmaf(sW3T[j * 64 + lane], mrow[j], acc);
        sF3[wave][lane] = fmaxf(acc, 0.f);
        __syncthreads();

        float a4 = b4[lane];
#pragma unroll 8
        for (int j = 0; j < 64; ++j)
            a4 = fmaf(sW4T[j * 64 + lane], sF3[wave][j], a4);
        if (act)
            fc4out[(size_t)c * 64 + lane] = fmaxf(a4, 0.f);
        __syncthreads();
    }
}

// ---------------- fc5 (67->3) + segment sums ----------------
__global__ __launch_bounds__(256) void k_fc5(
    const float* __restrict__ points, const int* __restrict__ cluster,
    const float* __restrict__ fc4, const float* __restrict__ W5,
    const float* __restrict__ b5, float* __restrict__ sums)
{
    int i = blockIdx.x * 256 + threadIdx.x;
    if (i >= N_PTS) return;
    const int c = cluster[i];
    const float p0 = points[(size_t)i * 3 + 0];
    const float p1 = points[(size_t)i * 3 + 1];
    const float p2 = points[(size_t)i * 3 + 2];
    const float* f4 = fc4 + (size_t)c * 64;

    float a0 = b5[0];
    a0 = fmaf(W5[0], p0, a0); a0 = fmaf(W5[1], p1, a0); a0 = fmaf(W5[2], p2, a0);
    float a1 = b5[1];
    a1 = fmaf(W5[67], p0, a1); a1 = fmaf(W5[68], p1, a1); a1 = fmaf(W5[69], p2, a1);
    float a2 = b5[2];
    a2 = fmaf(W5[134], p0, a2); a2 = fmaf(W5[135], p1, a2); a2 = fmaf(W5[136], p2, a2);

#pragma unroll
    for (int j = 0; j < 64; j += 4) {
        float4 v = *(const float4*)(f4 + j);
        a0 = fmaf(W5[3 + j + 0], v.x, a0);
        a0 = fmaf(W5[3 + j + 1], v.y, a0);
        a0 = fmaf(W5[3 + j + 2], v.z, a0);
        a0 = fmaf(W5[3 + j + 3], v.w, a0);
        a1 = fmaf(W5[70 + j + 0], v.x, a1);
        a1 = fmaf(W5[70 + j + 1], v.y, a1);
        a1 = fmaf(W5[70 + j + 2], v.z, a1);
        a1 = fmaf(W5[70 + j + 3], v.w, a1);
        a2 = fmaf(W5[137 + j + 0], v.x, a2);
        a2 = fmaf(W5[137 + j + 1], v.y, a2);
        a2 = fmaf(W5[137 + j + 2], v.z, a2);
        a2 = fmaf(W5[137 + j + 3], v.w, a2);
    }
    a0 = fmaxf(a0, 0.f);
    a1 = fmaxf(a1, 0.f);
    a2 = fmaxf(a2, 0.f);

    float* srow = sums + (size_t)c * 4;
    atomicAdd(srow + 0, a0);
    atomicAdd(srow + 1, a1);
    atomicAdd(srow + 2, a2);
    atomicAdd(srow + 3, 1.0f);
}

// ---------------- angles: sigmoid(sums / max(cnt,1)) ----------------
__global__ __launch_bounds__(256) void k_angles(
    const float* __restrict__ sums, float* __restrict__ angout)
{
    int c = blockIdx.x * 256 + threadIdx.x;
    if (c >= NC) return;
    const float cnt = fmaxf(sums[(size_t)c * 4 + 3], 1.f);
#pragma unroll
    for (int r = 0; r < 3; ++r) {
        float s = sums[(size_t)c * 4 + r] / cnt;
        angout[(size_t)c * 3 + r] = 1.f / (1.f + expf(-s));
    }
}

extern "C" void kernel_launch(void* const* d_in, const int* in_sizes, int n_in,
                              void* d_out, int out_size, void* d_ws, size_t ws_size,
                              hipStream_t stream) {
    const float* points  = (const float*)d_in[0];
    const float* inv     = (const float*)d_in[1];
    const int*   cluster = (const int*)d_in[2];
    const float* W1 = (const float*)d_in[3];
    const float* b1 = (const float*)d_in[4];
    const float* W2 = (const float*)d_in[5];
    const float* b2 = (const float*)d_in[6];
    const float* W3 = (const float*)d_in[7];
    const float* b3 = (const float*)d_in[8];
    const float* W4 = (const float*)d_in[9];
    const float* b4 = (const float*)d_in[10];
    const float* W5 = (const float*)d_in[11];
    const float* b5 = (const float*)d_in[12];

    float* out    = (float*)d_out;
    float* fc4out = out;                       // [C,64]
    float* angout = out + (size_t)NC * 64;     // [C,3]

    // workspace: mx [C,128] fp32 = 25.6 MB, sums [C,4] = 0.8 MB
    float* mx   = (float*)d_ws;
    float* sums = mx + (size_t)NC * 128;

    hipMemsetAsync(d_ws, 0, (size_t)(NC * 128 + NC * 4) * sizeof(float), stream);

    k_points <<<N_PTS / 256, 256, 0, stream>>>(inv, cluster, W1, b1, W2, b2, mx);
    k_cluster<<<1024, 256, 0, stream>>>(mx, W3, b3, W4, b4, fc4out);
    k_fc5    <<<N_PTS / 256, 256, 0, stream>>>(points, cluster, fc4out, W5, b5, sums);
    k_angles <<<(NC + 255) / 256, 256, 0, stream>>>(sums, angout);
}

// Round 2
// 699.742 us; speedup vs baseline: 4.3368x; 4.3368x over previous
//
#include <hip/hip_runtime.h>

#define N_PTS 1048576
#define NC 50000
#define SCAN_T 256
#define CHUNK ((NC + SCAN_T - 1) / SCAN_T)   // 196

// ---------------- counting sort: histogram ----------------
__global__ __launch_bounds__(256) void k_hist(
    const int* __restrict__ cluster, int* __restrict__ counts)
{
    int i = blockIdx.x * 256 + threadIdx.x;
    atomicAdd(counts + cluster[i], 1);
}

// ---------------- counting sort: exclusive scan (single block) ----------------
__global__ __launch_bounds__(SCAN_T) void k_scan(
    const int* __restrict__ counts, int* __restrict__ cursor)
{
    __shared__ int lsum[SCAN_T];
    const int tid = threadIdx.x;
    const int lo = tid * CHUNK, hi = min(lo + CHUNK, NC);
    int s = 0;
    for (int i = lo; i < hi; ++i) s += counts[i];
    lsum[tid] = s;
    __syncthreads();
    for (int d = 1; d < SCAN_T; d <<= 1) {
        int v = (tid >= d) ? lsum[tid - d] : 0;
        __syncthreads();
        lsum[tid] += v;
        __syncthreads();
    }
    int off = (tid > 0) ? lsum[tid - 1] : 0;
    for (int i = lo; i < hi; ++i) { cursor[i] = off; off += counts[i]; }
}

// ---------------- counting sort: scatter ----------------
__global__ __launch_bounds__(256) void k_scatter(
    const int* __restrict__ cluster, int* __restrict__ cursor,
    int* __restrict__ perm, int* __restrict__ pclus)
{
    int i = blockIdx.x * 256 + threadIdx.x;
    int c = cluster[i];
    int pos = atomicAdd(cursor + c, 1);
    perm[pos] = i;
    pclus[pos] = c;
}

// ---------------- point MLP fc1(4->64), fc2(64->128), segmented max ----------------
__global__ __launch_bounds__(256) void k_points_sorted(
    const float* __restrict__ inv_feats,
    const int* __restrict__ perm, const int* __restrict__ pclus,
    const float* __restrict__ W1, const float* __restrict__ b1,
    const float* __restrict__ W2, const float* __restrict__ b2,
    float* __restrict__ mx)
{
    const int t = blockIdx.x * 256 + threadIdx.x;   // grid covers N_PTS exactly
    const int p = perm[t];
    const int c = pclus[t];
    const float4 xf = *(const float4*)(inv_feats + (size_t)p * 4);

    float fc1[64];
#pragma unroll
    for (int k = 0; k < 64; ++k) {
        float acc = b1[k];
        acc = fmaf(W1[k * 4 + 0], xf.x, acc);
        acc = fmaf(W1[k * 4 + 1], xf.y, acc);
        acc = fmaf(W1[k * 4 + 2], xf.z, acc);
        acc = fmaf(W1[k * 4 + 3], xf.w, acc);
        fc1[k] = fmaxf(acc, 0.f);
    }

    // segment masks (cluster runs within the wave), computed once
    const int lane = threadIdx.x & 63;
    bool eq[6];
#pragma unroll
    for (int s = 0; s < 6; ++s) {
        int d = 1 << s;
        int cu = __shfl_up(c, d, 64);
        eq[s] = (lane >= d) && (cu == c);
    }
    const int cd = __shfl_down(c, 1, 64);
    const bool tail = (lane == 63) || (cd != c);

    int* mrow = (int*)(mx + (size_t)c * 128);
#pragma unroll 2
    for (int k = 0; k < 128; ++k) {
        float acc = b2[k];
#pragma unroll
        for (int j = 0; j < 64; ++j)
            acc = fmaf(W2[k * 64 + j], fc1[j], acc);
        acc = fmaxf(acc, 0.f);
        // segmented inclusive max-scan; segment tail holds the segment max
#pragma unroll
        for (int s = 0; s < 6; ++s) {
            float av = __shfl_up(acc, 1 << s, 64);
            if (eq[s]) acc = fmaxf(acc, av);
        }
        if (tail && acc > 0.f)
            atomicMax(mrow + k, __float_as_int(acc));
    }
}

// ---------------- cluster MLP: fc3 (128->64), fc4 (64->64) ----------------
__global__ __launch_bounds__(256) void k_cluster(
    const float* __restrict__ mx,
    const float* __restrict__ W3, const float* __restrict__ b3,
    const float* __restrict__ W4, const float* __restrict__ b4,
    float* __restrict__ fc4out)
{
    __shared__ float sW3T[128 * 64];
    __shared__ float sW4T[64 * 64];
    __shared__ float sF3[4][64];

    for (int t = threadIdx.x; t < 128 * 64; t += 256) {
        int r = t >> 7, cc = t & 127;
        sW3T[cc * 64 + r] = W3[t];
    }
    for (int t = threadIdx.x; t < 64 * 64; t += 256) {
        int r = t >> 6, cc = t & 63;
        sW4T[cc * 64 + r] = W4[t];
    }
    __syncthreads();

    const int wave = threadIdx.x >> 6;
    const int lane = threadIdx.x & 63;

    for (int base = blockIdx.x * 4; base < NC; base += gridDim.x * 4) {
        int c = base + wave;
        bool act = c < NC;
        int cs = __builtin_amdgcn_readfirstlane(act ? c : 0);
        const float* mrow = mx + (size_t)cs * 128;

        float acc = b3[lane];
#pragma unroll 8
        for (int j = 0; j < 128; ++j)
            acc = fmaf(sW3T[j * 64 + lane], mrow[j], acc);
        sF3[wave][lane] = fmaxf(acc, 0.f);
        __syncthreads();

        float a4 = b4[lane];
#pragma unroll 8
        for (int j = 0; j < 64; ++j)
            a4 = fmaf(sW4T[j * 64 + lane], sF3[wave][j], a4);
        if (act)
            fc4out[(size_t)c * 64 + lane] = fmaxf(a4, 0.f);
        __syncthreads();
    }
}

// ---------------- fc5 (67->3) + segmented sums ----------------
__global__ __launch_bounds__(256) void k_fc5_sorted(
    const float* __restrict__ points,
    const int* __restrict__ perm, const int* __restrict__ pclus,
    const float* __restrict__ fc4, const float* __restrict__ W5,
    const float* __restrict__ b5, float* __restrict__ sums)
{
    const int t = blockIdx.x * 256 + threadIdx.x;
    const int p = perm[t];
    const int c = pclus[t];
    const float p0 = points[(size_t)p * 3 + 0];
    const float p1 = points[(size_t)p * 3 + 1];
    const float p2 = points[(size_t)p * 3 + 2];
    const float* f4 = fc4 + (size_t)c * 64;   // lanes mostly share c -> L1 broadcast

    float a0 = b5[0];
    a0 = fmaf(W5[0], p0, a0); a0 = fmaf(W5[1], p1, a0); a0 = fmaf(W5[2], p2, a0);
    float a1 = b5[1];
    a1 = fmaf(W5[67], p0, a1); a1 = fmaf(W5[68], p1, a1); a1 = fmaf(W5[69], p2, a1);
    float a2 = b5[2];
    a2 = fmaf(W5[134], p0, a2); a2 = fmaf(W5[135], p1, a2); a2 = fmaf(W5[136], p2, a2);

#pragma unroll
    for (int j = 0; j < 64; j += 4) {
        float4 v = *(const float4*)(f4 + j);
        a0 = fmaf(W5[3 + j + 0], v.x, a0);
        a0 = fmaf(W5[3 + j + 1], v.y, a0);
        a0 = fmaf(W5[3 + j + 2], v.z, a0);
        a0 = fmaf(W5[3 + j + 3], v.w, a0);
        a1 = fmaf(W5[70 + j + 0], v.x, a1);
        a1 = fmaf(W5[70 + j + 1], v.y, a1);
        a1 = fmaf(W5[70 + j + 2], v.z, a1);
        a1 = fmaf(W5[70 + j + 3], v.w, a1);
        a2 = fmaf(W5[137 + j + 0], v.x, a2);
        a2 = fmaf(W5[137 + j + 1], v.y, a2);
        a2 = fmaf(W5[137 + j + 2], v.z, a2);
        a2 = fmaf(W5[137 + j + 3], v.w, a2);
    }
    a0 = fmaxf(a0, 0.f);
    a1 = fmaxf(a1, 0.f);
    a2 = fmaxf(a2, 0.f);

    const int lane = threadIdx.x & 63;
    bool eq[6];
#pragma unroll
    for (int s = 0; s < 6; ++s) {
        int d = 1 << s;
        int cu = __shfl_up(c, d, 64);
        eq[s] = (lane >= d) && (cu == c);
    }
    const int cd = __shfl_down(c, 1, 64);
    const bool tail = (lane == 63) || (cd != c);

    // segmented inclusive sum-scan
#pragma unroll
    for (int s = 0; s < 6; ++s) {
        float v0 = __shfl_up(a0, 1 << s, 64);
        float v1 = __shfl_up(a1, 1 << s, 64);
        float v2 = __shfl_up(a2, 1 << s, 64);
        if (eq[s]) { a0 += v0; a1 += v1; a2 += v2; }
    }
    if (tail) {
        float* srow = sums + (size_t)c * 3;
        atomicAdd(srow + 0, a0);
        atomicAdd(srow + 1, a1);
        atomicAdd(srow + 2, a2);
    }
}

// ---------------- angles: sigmoid(sums / max(cnt,1)) ----------------
__global__ __launch_bounds__(256) void k_angles(
    const float* __restrict__ sums, const int* __restrict__ counts,
    float* __restrict__ angout)
{
    int c = blockIdx.x * 256 + threadIdx.x;
    if (c >= NC) return;
    const float cnt = fmaxf((float)counts[c], 1.f);
#pragma unroll
    for (int r = 0; r < 3; ++r) {
        float s = sums[(size_t)c * 3 + r] / cnt;
        angout[(size_t)c * 3 + r] = 1.f / (1.f + expf(-s));
    }
}

extern "C" void kernel_launch(void* const* d_in, const int* in_sizes, int n_in,
                              void* d_out, int out_size, void* d_ws, size_t ws_size,
                              hipStream_t stream) {
    const float* points  = (const float*)d_in[0];
    const float* inv     = (const float*)d_in[1];
    const int*   cluster = (const int*)d_in[2];
    const float* W1 = (const float*)d_in[3];
    const float* b1 = (const float*)d_in[4];
    const float* W2 = (const float*)d_in[5];
    const float* b2 = (const float*)d_in[6];
    const float* W3 = (const float*)d_in[7];
    const float* b3 = (const float*)d_in[8];
    const float* W4 = (const float*)d_in[9];
    const float* b4 = (const float*)d_in[10];
    const float* W5 = (const float*)d_in[11];
    const float* b5 = (const float*)d_in[12];

    float* out    = (float*)d_out;
    float* fc4out = out;                       // [C,64]
    float* angout = out + (size_t)NC * 64;     // [C,3]

    // workspace layout (zeroed region first):
    //   counts [NC] int | sums [NC*3] f32 | mx [NC*128] f32 || cursor [NC] | perm [N] | pclus [N]
    int*   counts = (int*)d_ws;
    float* sums   = (float*)(counts + NC);
    float* mx     = sums + (size_t)NC * 3;
    int*   cursor = (int*)(mx + (size_t)NC * 128);
    int*   perm   = cursor + NC;
    int*   pclus  = perm + N_PTS;

    hipMemsetAsync(d_ws, 0, (size_t)(NC + NC * 3 + NC * 128) * sizeof(float), stream);

    k_hist          <<<N_PTS / 256, 256, 0, stream>>>(cluster, counts);
    k_scan          <<<1, SCAN_T, 0, stream>>>(counts, cursor);
    k_scatter       <<<N_PTS / 256, 256, 0, stream>>>(cluster, cursor, perm, pclus);
    k_points_sorted <<<N_PTS / 256, 256, 0, stream>>>(inv, perm, pclus, W1, b1, W2, b2, mx);
    k_cluster       <<<1024, 256, 0, stream>>>(mx, W3, b3, W4, b4, fc4out);
    k_fc5_sorted    <<<N_PTS / 256, 256, 0, stream>>>(points, perm, pclus, fc4out, W5, b5, sums);
    k_angles        <<<(NC + 255) / 256, 256, 0, stream>>>(sums, counts, angout);
}